// Round 1
// baseline (13727.464 us; speedup 1.0000x reference)
//
#include <hip/hip_runtime.h>
#include <hip/hip_cooperative_groups.h>

namespace cg = cooperative_groups;

typedef __attribute__((ext_vector_type(8))) short short8;
typedef __attribute__((ext_vector_type(4))) float f32x4;

__device__ __forceinline__ unsigned short f2bf(float f){
  unsigned u = __float_as_uint(f);
  u += 0x7FFFu + ((u >> 16) & 1u);
  return (unsigned short)(u >> 16);
}
__device__ __forceinline__ float sigm(float x){ return 1.f / (1.f + expf(-x)); }

// ---------- prep kernels ----------

// embed fp32 -> bf16 (16,384,000 elements, 4/thread, grid exactly covers)
__global__ void k_embed_cvt(const float* __restrict__ e, unsigned short* __restrict__ ebf){
  long i = ((long)blockIdx.x * 256 + threadIdx.x) * 4;
  float4 v = *(const float4*)(e + i);
  ushort4 o;
  o.x = f2bf(v.x); o.y = f2bf(v.y); o.z = f2bf(v.z); o.w = f2bf(v.w);
  *(ushort4*)(ebf + i) = o;
}

// zero h1 ping buffer 0, h2seq row 0 (fp32), h2bf rows t=0; b2c = b_ih2+b_hh2
__global__ void k_prep_misc(const float* __restrict__ b_ih2, const float* __restrict__ b_hh2,
                            float* __restrict__ b2c, float* __restrict__ h1buf0,
                            float* __restrict__ h2row0, unsigned short* __restrict__ h2bf0){
  int i = blockIdx.x * 256 + threadIdx.x;
  if(i < 8192){ h1buf0[i] = 0.f; h2row0[i] = 0.f; h2bf0[i] = 0; }
  if(i < 2048){ b2c[i] = b_ih2[i] + b_hh2[i]; }
}

// transpose the three recurrent weight matrices (2048x512 -> 512x2048), output-indexed
__global__ void k_transpose3(const float* __restrict__ w1, const float* __restrict__ w2a,
                             const float* __restrict__ w2b, float* __restrict__ t1,
                             float* __restrict__ t2a, float* __restrict__ t2b){
  unsigned i = blockIdx.x * 256 + threadIdx.x;   // 0 .. 3*2^20
  unsigned mat = i >> 20, r = i & 1048575u;
  unsigned k = r >> 11, j = r & 2047u;           // j fastest -> coalesced writes
  const float* s = (mat == 0) ? w1 : (mat == 1 ? w2a : w2b);
  float* d = (mat == 0) ? t1 : (mat == 1 ? t2a : t2b);
  d[k * 2048 + j] = s[j * 512 + k];
}

// a1c[b][j] = b_ih1[j] + b_hh1[j] + sum_{k<512} embed[words[b][0]][k] * w_ih1[j][k]
// (x = [x0, zeros] so only first 512 of the 1024 K dims contribute)
__global__ void k_a1const(const int* __restrict__ words, const float* __restrict__ embed,
                          const float* __restrict__ w_ih1, const float* __restrict__ b_ih1,
                          const float* __restrict__ b_hh1, float* __restrict__ a1c){
  int bb = threadIdx.x & 15, jj = threadIdx.x >> 4;
  int j = blockIdx.x * 16 + jj;
  const float* x0 = embed + (long)words[bb * 256] * 512;
  const float* wr = w_ih1 + (long)j * 1024;
  float acc = 0.f;
  for(int k = 0; k < 512; k += 4){
    float4 a = *(const float4*)(x0 + k);
    float4 b = *(const float4*)(wr + k);
    acc += a.x*b.x + a.y*b.y + a.z*b.z + a.w*b.w;
  }
  a1c[bb * 2048 + j] = acc + b_ih1[j] + b_hh1[j];
}

// ---------- recurrent cooperative kernel ----------
// 192 blocks: blocks [0,64) = layer-1, blocks [64,192) = layer-2 (one step behind).
// One grid.sync per step. c-states live in registers of the "update" threads.
__global__ void __launch_bounds__(256, 1) k_recur(
    const float* __restrict__ wT1, const float* __restrict__ wT2a, const float* __restrict__ wT2b,
    const float* __restrict__ a1c, const float* __restrict__ b2c,
    float* __restrict__ h1buf, float* __restrict__ h2seq, unsigned short* __restrict__ h2bf){
  cg::grid_group grid = cg::this_grid();
  const int bl = blockIdx.x, tid = threadIdx.x;
  if(bl < 64){
    // layer 1: this block owns hidden units [ubase, ubase+8), all 16 batches, all 4 gates
    const int ubase = bl * 8;
    const int cc = tid & 7, bb = (tid >> 3) & 15, kh = tid >> 7;   // 8 x 16 x 2
    const int j4 = (cc >> 1) * 512 + ubase + (cc & 1) * 4;         // float4 over gate dim
    const int k0 = kh * 256;
    __shared__ float sg[2][16][32];
    float c1 = 0.f;
    const int uu = tid & 7, ub = tid >> 3;                          // valid when tid<128
    for(int s = 1; s <= 256; ++s){
      if(s <= 255){
        const float* hp = h1buf + ((s - 1) & 1) * 8192 + bb * 512;
        float ax = 0.f, ay = 0.f, az = 0.f, aw = 0.f;
        for(int k = k0; k < k0 + 256; k += 4){
          float4 h4 = *(const float4*)(hp + k);
          #pragma unroll
          for(int d = 0; d < 4; ++d){
            float4 w4 = *(const float4*)(wT1 + (long)(k + d) * 2048 + j4);
            float hd = (d == 0) ? h4.x : (d == 1) ? h4.y : (d == 2) ? h4.z : h4.w;
            ax += hd * w4.x; ay += hd * w4.y; az += hd * w4.z; aw += hd * w4.w;
          }
        }
        sg[kh][bb][cc*4+0] = ax; sg[kh][bb][cc*4+1] = ay;
        sg[kh][bb][cc*4+2] = az; sg[kh][bb][cc*4+3] = aw;
        __syncthreads();
        if(tid < 128){
          float gt[4];
          #pragma unroll
          for(int g = 0; g < 4; ++g){
            int idx = g * 8 + uu;
            gt[g] = sg[0][ub][idx] + sg[1][ub][idx] + a1c[ub * 2048 + g * 512 + ubase + uu];
          }
          float i_ = sigm(gt[0]), f_ = sigm(gt[1]), g_ = tanhf(gt[2]), o_ = sigm(gt[3]);
          c1 = f_ * c1 + i_ * g_;
          h1buf[(s & 1) * 8192 + ub * 512 + ubase + uu] = o_ * tanhf(c1);
        }
      }
      grid.sync();
    }
  } else {
    // layer 2: block owns hidden units [ubase, ubase+4); combined K=1024 (h1 then h2_prev)
    const int ubase = (bl - 64) * 4;
    const int cc = tid & 3, bb = (tid >> 2) & 15, kq = tid >> 6;   // 4 x 16 x 4
    const int j4 = cc * 512 + ubase;
    __shared__ float sg2[4][16][16];
    float c2 = 0.f;
    const int uu = tid & 3, ub = tid >> 2;                          // valid when tid<64
    for(int s = 1; s <= 256; ++s){
      if(s >= 2){
        const int t = s - 1;                                        // computing h2(t)
        const float* hsrc; const float* W; int k0;
        if(kq < 2){ hsrc = h1buf + ((s - 1) & 1) * 8192 + bb * 512; W = wT2a; k0 = kq * 256; }
        else      { hsrc = h2seq + (long)(t - 1) * 8192 + bb * 512; W = wT2b; k0 = (kq - 2) * 256; }
        float ax = 0.f, ay = 0.f, az = 0.f, aw = 0.f;
        for(int k = k0; k < k0 + 256; k += 4){
          float4 h4 = *(const float4*)(hsrc + k);
          #pragma unroll
          for(int d = 0; d < 4; ++d){
            float4 w4 = *(const float4*)(W + (long)(k + d) * 2048 + j4);
            float hd = (d == 0) ? h4.x : (d == 1) ? h4.y : (d == 2) ? h4.z : h4.w;
            ax += hd * w4.x; ay += hd * w4.y; az += hd * w4.z; aw += hd * w4.w;
          }
        }
        sg2[kq][bb][cc*4+0] = ax; sg2[kq][bb][cc*4+1] = ay;
        sg2[kq][bb][cc*4+2] = az; sg2[kq][bb][cc*4+3] = aw;
        __syncthreads();
        if(tid < 64){
          float gt[4];
          #pragma unroll
          for(int g = 0; g < 4; ++g){
            int idx = g * 4 + uu;
            gt[g] = sg2[0][ub][idx] + sg2[1][ub][idx] + sg2[2][ub][idx] + sg2[3][ub][idx]
                  + b2c[g * 512 + ubase + uu];
          }
          float i_ = sigm(gt[0]), f_ = sigm(gt[1]), g_ = tanhf(gt[2]), o_ = sigm(gt[3]);
          c2 = f_ * c2 + i_ * g_;
          float h2 = o_ * tanhf(c2);
          h2seq[(long)t * 8192 + ub * 512 + ubase + uu] = h2;
          h2bf[((long)t * 16 + ub) * 512 + ubase + uu] = f2bf(h2);
        }
      }
      grid.sync();
    }
  }
}

// ---------- projection GEMM: out[b][t][v] = h2(t) . embed[v] + fc_b[v]; t==0 -> 0 ----------
// A = h2bf (4096 x 512, row m = t*16+b), B = embed_bf (32000 x 512), both K-contiguous.
__global__ void __launch_bounds__(256, 2) k_proj(const unsigned short* __restrict__ A,
                                                 const unsigned short* __restrict__ Bm,
                                                 const float* __restrict__ fc_b,
                                                 float* __restrict__ out){
  __shared__ __align__(16) unsigned short As[4096];   // [128][32]
  __shared__ __align__(16) unsigned short Bs[4096];   // [128][32]
  const int tid = threadIdx.x;
  const int lane = tid & 63, w = tid >> 6;
  const int wr = w >> 1, wc = w & 1;
  const long mbase = (long)blockIdx.y * 128;
  const long nbase = (long)blockIdx.x * 128;
  f32x4 acc[4][4] = {};

  const int lrow = lane >> 2;        // 0..15 rows within a wave's 16-row stripe
  const int lcol = (lane & 3) * 8;   // element col offset within BK=32
  for(int kt = 0; kt < 16; ++kt){
    #pragma unroll
    for(int r = 0; r < 2; ++r){
      const unsigned short* ga = A  + (mbase + r*64 + w*16 + lrow) * 512 + kt*32 + lcol;
      __builtin_amdgcn_global_load_lds((const __attribute__((address_space(1))) void*)ga,
          (__attribute__((address_space(3))) void*)((char*)As + r*4096 + w*1024), 16, 0, 0);
      const unsigned short* gb = Bm + (nbase + r*64 + w*16 + lrow) * 512 + kt*32 + lcol;
      __builtin_amdgcn_global_load_lds((const __attribute__((address_space(1))) void*)gb,
          (__attribute__((address_space(3))) void*)((char*)Bs + r*4096 + w*1024), 16, 0, 0);
    }
    __syncthreads();
    short8 af[4], bf[4];
    const int kro = (lane >> 4) * 8;
    #pragma unroll
    for(int m = 0; m < 4; ++m){
      af[m] = *(const short8*)(As + (wr*64 + m*16 + (lane & 15)) * 32 + kro);
      bf[m] = *(const short8*)(Bs + (wc*64 + m*16 + (lane & 15)) * 32 + kro);
    }
    #pragma unroll
    for(int m = 0; m < 4; ++m){
      #pragma unroll
      for(int n = 0; n < 4; ++n){
        acc[m][n] = __builtin_amdgcn_mfma_f32_16x16x32_bf16(af[m], bf[n], acc[m][n], 0, 0, 0);
      }
    }
    __syncthreads();
  }
  const int crow0 = (lane >> 4) * 4;
  const int ccol = lane & 15;
  float fb[4];
  #pragma unroll
  for(int n = 0; n < 4; ++n) fb[n] = fc_b[nbase + wc*64 + n*16 + ccol];
  #pragma unroll
  for(int m = 0; m < 4; ++m){
    #pragma unroll
    for(int j = 0; j < 4; ++j){
      long rr = mbase + wr*64 + m*16 + crow0 + j;
      int t = (int)(rr >> 4), b = (int)(rr & 15);
      float* orow = out + ((long)b * 256 + t) * 32000;
      #pragma unroll
      for(int n = 0; n < 4; ++n){
        float v = (t == 0) ? 0.f : (acc[m][n][j] + fb[n]);
        orow[nbase + wc*64 + n*16 + ccol] = v;
      }
    }
  }
}

extern "C" void kernel_launch(void* const* d_in, const int* in_sizes, int n_in,
                              void* d_out, int out_size, void* d_ws, size_t ws_size,
                              hipStream_t stream){
  const int*   words = (const int*)  d_in[0];
  const float* embed = (const float*)d_in[1];
  const float* fc_b  = (const float*)d_in[2];
  const float* w_ih1 = (const float*)d_in[3];
  const float* w_hh1 = (const float*)d_in[4];
  const float* b_ih1 = (const float*)d_in[5];
  const float* b_hh1 = (const float*)d_in[6];
  const float* w_ih2 = (const float*)d_in[7];
  const float* w_hh2 = (const float*)d_in[8];
  const float* b_ih2 = (const float*)d_in[9];
  const float* b_hh2 = (const float*)d_in[10];
  float* out = (float*)d_out;
  char* ws = (char*)d_ws;

  unsigned short* embed_bf = (unsigned short*)(ws + 0);          // 32,768,000 B
  unsigned short* h2bf     = (unsigned short*)(ws + 32768000);   //  4,194,304 B (4096x512)
  float* h2seq = (float*)(ws + 36962304);                        //  8,388,608 B (256x16x512)
  float* h1buf = (float*)(ws + 45350912);                        //     65,536 B (2x16x512)
  float* a1c   = (float*)(ws + 45416448);                        //    131,072 B (16x2048)
  float* b2c   = (float*)(ws + 45547520);                        //      8,192 B
  float* wT1   = (float*)(ws + 45555712);                        //  4,194,304 B (512x2048)
  float* wT2a  = (float*)(ws + 49750016);                        //  4,194,304 B
  float* wT2b  = (float*)(ws + 53944320);                        //  4,194,304 B
  // total 58,138,624 B

  k_embed_cvt<<<16000, 256, 0, stream>>>(embed, embed_bf);
  k_prep_misc<<<32, 256, 0, stream>>>(b_ih2, b_hh2, b2c, h1buf, h2seq, h2bf);
  k_transpose3<<<12288, 256, 0, stream>>>(w_hh1, w_ih2, w_hh2, wT1, wT2a, wT2b);
  k_a1const<<<128, 256, 0, stream>>>(words, embed, w_ih1, b_ih1, b_hh1, a1c);

  void* args[8];
  args[0] = (void*)&wT1;  args[1] = (void*)&wT2a; args[2] = (void*)&wT2b;
  args[3] = (void*)&a1c;  args[4] = (void*)&b2c;
  args[5] = (void*)&h1buf; args[6] = (void*)&h2seq; args[7] = (void*)&h2bf;
  hipLaunchCooperativeKernel((const void*)k_recur, dim3(192), dim3(256), args, 0, stream);

  k_proj<<<dim3(250, 32), 256, 0, stream>>>(h2bf, embed_bf, fc_b, out);
}

// Round 2
// 4078.893 us; speedup vs baseline: 3.3655x; 3.3655x over previous
//
#include <hip/hip_runtime.h>

typedef __attribute__((ext_vector_type(8))) short short8;
typedef __attribute__((ext_vector_type(4))) float f32x4;

__device__ __forceinline__ unsigned short f2bf(float f){
  unsigned u = __float_as_uint(f);
  u += 0x7FFFu + ((u >> 16) & 1u);
  return (unsigned short)(u >> 16);
}
__device__ __forceinline__ float sigm(float x){ return 1.f / (1.f + expf(-x)); }
__device__ __forceinline__ int aldr(int* p){
  return __hip_atomic_load(p, __ATOMIC_RELAXED, __HIP_MEMORY_SCOPE_AGENT);
}

// ---------- prep kernels ----------

__global__ void k_embed_cvt(const float* __restrict__ e, unsigned short* __restrict__ ebf){
  long i = ((long)blockIdx.x * 256 + threadIdx.x) * 4;
  float4 v = *(const float4*)(e + i);
  ushort4 o;
  o.x = f2bf(v.x); o.y = f2bf(v.y); o.z = f2bf(v.z); o.w = f2bf(v.w);
  *(ushort4*)(ebf + i) = o;
}

// zero h1ring slot0, h2ring slot0, h2bf rows t=0, counters; b2c = b_ih2+b_hh2
__global__ void k_prep_misc(const float* __restrict__ b_ih2, const float* __restrict__ b_hh2,
                            float* __restrict__ b2c, float* __restrict__ h1ring0,
                            float* __restrict__ h2ring0, unsigned short* __restrict__ h2bf0,
                            int* __restrict__ cnts){
  int i = blockIdx.x * 256 + threadIdx.x;
  if(i < 8192){ h1ring0[i] = 0.f; h2ring0[i] = 0.f; h2bf0[i] = 0; }
  if(i < 2048){ b2c[i] = b_ih2[i] + b_hh2[i]; }
  if(i < 64){ cnts[i] = 0; }
}

// a1c[b][j] = b_ih1[j] + b_hh1[j] + sum_{k<512} embed[words[b][0]][k] * w_ih1[j][k]
__global__ void k_a1const(const int* __restrict__ words, const float* __restrict__ embed,
                          const float* __restrict__ w_ih1, const float* __restrict__ b_ih1,
                          const float* __restrict__ b_hh1, float* __restrict__ a1c){
  int bb = threadIdx.x & 15, jj = threadIdx.x >> 4;
  int j = blockIdx.x * 16 + jj;
  const float* x0 = embed + (long)words[bb * 256] * 512;
  const float* wr = w_ih1 + (long)j * 1024;
  float acc = 0.f;
  for(int k = 0; k < 512; k += 4){
    float4 a = *(const float4*)(x0 + k);
    float4 b = *(const float4*)(wr + k);
    acc += a.x*b.x + a.y*b.y + a.z*b.z + a.w*b.w;
  }
  a1c[bb * 2048 + j] = acc + b_ih1[j] + b_hh1[j];
}

// ---------- recurrent kernel: weight-stationary, split flag-barriers ----------
// blocks [0,64): layer-1, 8 hidden units each. blocks [64,192): layer-2, 4 units each.
// L1 writes h1 into a 64-deep ring and never waits on L2 except for ring reuse.
__global__ void __launch_bounds__(256, 1) k_recur(
    const float* __restrict__ w_hh1, const float* __restrict__ w_ih2, const float* __restrict__ w_hh2,
    const float* __restrict__ a1c, const float* __restrict__ b2c,
    float* __restrict__ h1ring, float* __restrict__ h2ring, unsigned short* __restrict__ h2bf,
    int* cnt1, int* cnt2){
  __shared__ float smem[16384];   // 64 KiB: h-stage (reused for partials) + red at [8192..]
  const int bl = blockIdx.x, tid = threadIdx.x;

  if(bl < 64){
    // ---- layer 1 ----
    const int ubase = bl * 8;
    const int cgrp = tid & 7, kg = (tid >> 3) & 15, bh = tid >> 7;
    const int xr = kg & 7;
    // weights in registers: 4 cols x 32 k   (col c = cgrp*4+cc => gate cgrp>>1, unit (cgrp&1)*4+cc)
    float4 wr[4][8];
    {
      const int j0 = (cgrp >> 1) * 512 + ubase + (cgrp & 1) * 4;
      #pragma unroll
      for(int cc = 0; cc < 4; ++cc)
        #pragma unroll
        for(int j = 0; j < 8; ++j)
          wr[cc][j] = *(const float4*)(w_hh1 + (long)(j0 + cc) * 512 + kg * 32 + j * 4);
    }
    float c1 = 0.f;
    float a1g[4] = {0.f, 0.f, 0.f, 0.f};
    const int au = tid & 7, ab = tid >> 3;
    if(tid < 128){
      #pragma unroll
      for(int g = 0; g < 4; ++g) a1g[g] = a1c[ab * 2048 + g * 512 + ubase + au];
    }
    for(int s = 1; s <= 255; ++s){
      if(tid == 0){
        if(s > 1){ int tgt = 64 * (s - 1); while(aldr(cnt1) < tgt) __builtin_amdgcn_s_sleep(1); }
        if(s >= 65){ int tgt = 128 * (s - 64); while(aldr(cnt2) < tgt) __builtin_amdgcn_s_sleep(1); }
        __threadfence();                      // acquire: invalidate L1/L2 before reading fresh h
      }
      __syncthreads();
      { // stage h1(s-1): 32 KiB, XOR-swizzled so dot-phase reads are conflict-free
        const float* src = h1ring + ((s - 1) & 63) * 8192;
        #pragma unroll
        for(int j = 0; j < 8; ++j){
          int v = tid + 256 * j;
          *(float4*)(smem + 4 * (v ^ ((v >> 3) & 7))) = *(const float4*)(src + 4 * v);
        }
      }
      __syncthreads();
      float4 acc[8] = {};
      #pragma unroll
      for(int b8 = 0; b8 < 8; ++b8){
        const int b = bh * 8 + b8;
        const float* hb = smem + b * 512 + kg * 32;
        float4 hv[8];
        #pragma unroll
        for(int j = 0; j < 8; ++j) hv[j] = *(const float4*)(hb + 4 * (j ^ xr));
        #pragma unroll
        for(int j = 0; j < 8; ++j){
          float4 h4 = hv[j];
          acc[b8].x += h4.x*wr[0][j].x + h4.y*wr[0][j].y + h4.z*wr[0][j].z + h4.w*wr[0][j].w;
          acc[b8].y += h4.x*wr[1][j].x + h4.y*wr[1][j].y + h4.z*wr[1][j].z + h4.w*wr[1][j].w;
          acc[b8].z += h4.x*wr[2][j].x + h4.y*wr[2][j].y + h4.z*wr[2][j].z + h4.w*wr[2][j].w;
          acc[b8].w += h4.x*wr[3][j].x + h4.y*wr[3][j].y + h4.z*wr[3][j].z + h4.w*wr[3][j].w;
        }
      }
      __syncthreads();                        // all hs reads done -> reuse smem for partials
      #pragma unroll
      for(int b8 = 0; b8 < 8; ++b8){
        int b = bh * 8 + b8;
        *(float4*)(smem + (kg * 16 + b) * 32 + cgrp * 4) = acc[b8];
      }
      __syncthreads();
      #pragma unroll
      for(int q = 0; q < 2; ++q){            // reduce over 16 kg
        int p = tid * 2 + q, b = p >> 5, col = p & 31;
        float sum = 0.f;
        #pragma unroll
        for(int k2 = 0; k2 < 16; ++k2) sum += smem[k2 * 512 + b * 32 + col];
        smem[8192 + b * 32 + col] = sum;
      }
      __syncthreads();
      if(tid < 128){
        float g0 = smem[8192 + ab * 32 +  0 + au] + a1g[0];
        float g1 = smem[8192 + ab * 32 +  8 + au] + a1g[1];
        float g2 = smem[8192 + ab * 32 + 16 + au] + a1g[2];
        float g3 = smem[8192 + ab * 32 + 24 + au] + a1g[3];
        c1 = sigm(g1) * c1 + sigm(g0) * tanhf(g2);
        float h = sigm(g3) * tanhf(c1);
        h1ring[(s & 63) * 8192 + ab * 512 + ubase + au] = h;
      }
      __syncthreads();                        // drains vmcnt(0): all stores in L2
      if(tid == 0)
        __hip_atomic_fetch_add(cnt1, 1, __ATOMIC_RELEASE, __HIP_MEMORY_SCOPE_AGENT);
    }
  } else {
    // ---- layer 2 ----
    const int ubase = (bl - 64) * 4;
    const int cgrp = tid & 3, kg = (tid >> 2) & 31, bh = tid >> 7;
    const int xr = kg & 7;
    float4 wr[4][8];   // 4 cols x 32 k; kg<16 -> w_ih2 (K = h1), else w_hh2 (K = h2prev)
    {
      const float* W = (kg < 16) ? w_ih2 : w_hh2;
      const int ko = (kg & 15) * 32;
      #pragma unroll
      for(int cc = 0; cc < 4; ++cc){
        const int row = cgrp * 512 + ubase + cc;
        #pragma unroll
        for(int j = 0; j < 8; ++j)
          wr[cc][j] = *(const float4*)(W + (long)row * 512 + ko + j * 4);
      }
    }
    float c2 = 0.f;
    float b2g[4] = {0.f, 0.f, 0.f, 0.f};
    const int au = tid & 3, ab = tid >> 2;
    if(tid < 64){
      #pragma unroll
      for(int g = 0; g < 4; ++g) b2g[g] = b2c[g * 512 + ubase + au];
    }
    for(int t = 1; t <= 255; ++t){
      if(tid == 0){
        { int tgt = 64 * t; while(aldr(cnt1) < tgt) __builtin_amdgcn_s_sleep(1); }
        if(t > 1){ int tgt = 128 * (t - 1); while(aldr(cnt2) < tgt) __builtin_amdgcn_s_sleep(1); }
        __threadfence();
      }
      __syncthreads();
      { // stage [h1(t) | h2(t-1)]: 64 KiB; j == batch, lanes<128 read h1 part (wave-uniform)
        const float* s1 = h1ring + (t & 63) * 8192;
        const float* s2 = h2ring + ((t - 1) & 1) * 8192;
        #pragma unroll
        for(int j = 0; j < 16; ++j){
          int v = tid + 256 * j;
          float4 val = (tid < 128) ? *(const float4*)(s1 + j * 512 + tid * 4)
                                   : *(const float4*)(s2 + j * 512 + (tid - 128) * 4);
          *(float4*)(smem + 4 * (v ^ ((v >> 3) & 7))) = val;
        }
      }
      __syncthreads();
      float4 acc[8] = {};
      #pragma unroll
      for(int b8 = 0; b8 < 8; ++b8){
        const int b = bh * 8 + b8;
        const float* hb = smem + b * 1024 + kg * 32;
        float4 hv[8];
        #pragma unroll
        for(int j = 0; j < 8; ++j) hv[j] = *(const float4*)(hb + 4 * (j ^ xr));
        #pragma unroll
        for(int j = 0; j < 8; ++j){
          float4 h4 = hv[j];
          acc[b8].x += h4.x*wr[0][j].x + h4.y*wr[0][j].y + h4.z*wr[0][j].z + h4.w*wr[0][j].w;
          acc[b8].y += h4.x*wr[1][j].x + h4.y*wr[1][j].y + h4.z*wr[1][j].z + h4.w*wr[1][j].w;
          acc[b8].z += h4.x*wr[2][j].x + h4.y*wr[2][j].y + h4.z*wr[2][j].z + h4.w*wr[2][j].w;
          acc[b8].w += h4.x*wr[3][j].x + h4.y*wr[3][j].y + h4.z*wr[3][j].z + h4.w*wr[3][j].w;
        }
      }
      __syncthreads();
      #pragma unroll
      for(int b8 = 0; b8 < 8; ++b8){
        int b = bh * 8 + b8;
        *(float4*)(smem + (kg * 16 + b) * 16 + cgrp * 4) = acc[b8];
      }
      __syncthreads();
      {
        int b = tid >> 4, col = tid & 15;
        float sum = 0.f;
        #pragma unroll
        for(int k2 = 0; k2 < 32; ++k2) sum += smem[k2 * 256 + b * 16 + col];
        smem[8192 + b * 16 + col] = sum;
      }
      __syncthreads();
      if(tid < 64){
        float g0 = smem[8192 + ab * 16 +  0 + au] + b2g[0];
        float g1 = smem[8192 + ab * 16 +  4 + au] + b2g[1];
        float g2 = smem[8192 + ab * 16 +  8 + au] + b2g[2];
        float g3 = smem[8192 + ab * 16 + 12 + au] + b2g[3];
        c2 = sigm(g1) * c2 + sigm(g0) * tanhf(g2);
        float h = sigm(g3) * tanhf(c2);
        h2ring[(t & 1) * 8192 + ab * 512 + ubase + au] = h;
        h2bf[((long)t * 16 + ab) * 512 + ubase + au] = f2bf(h);
      }
      __syncthreads();
      if(tid == 0)
        __hip_atomic_fetch_add(cnt2, 1, __ATOMIC_RELEASE, __HIP_MEMORY_SCOPE_AGENT);
    }
  }
}

// ---------- projection GEMM (unchanged from R1, passed) ----------
__global__ void __launch_bounds__(256, 2) k_proj(const unsigned short* __restrict__ A,
                                                 const unsigned short* __restrict__ Bm,
                                                 const float* __restrict__ fc_b,
                                                 float* __restrict__ out){
  __shared__ __align__(16) unsigned short As[4096];   // [128][32]
  __shared__ __align__(16) unsigned short Bs[4096];   // [128][32]
  const int tid = threadIdx.x;
  const int lane = tid & 63, w = tid >> 6;
  const int wr = w >> 1, wc = w & 1;
  const long mbase = (long)blockIdx.y * 128;
  const long nbase = (long)blockIdx.x * 128;
  f32x4 acc[4][4] = {};

  const int lrow = lane >> 2;
  const int lcol = (lane & 3) * 8;
  for(int kt = 0; kt < 16; ++kt){
    #pragma unroll
    for(int r = 0; r < 2; ++r){
      const unsigned short* ga = A  + (mbase + r*64 + w*16 + lrow) * 512 + kt*32 + lcol;
      __builtin_amdgcn_global_load_lds((const __attribute__((address_space(1))) void*)ga,
          (__attribute__((address_space(3))) void*)((char*)As + r*4096 + w*1024), 16, 0, 0);
      const unsigned short* gb = Bm + (nbase + r*64 + w*16 + lrow) * 512 + kt*32 + lcol;
      __builtin_amdgcn_global_load_lds((const __attribute__((address_space(1))) void*)gb,
          (__attribute__((address_space(3))) void*)((char*)Bs + r*4096 + w*1024), 16, 0, 0);
    }
    __syncthreads();
    short8 af[4], bf[4];
    const int kro = (lane >> 4) * 8;
    #pragma unroll
    for(int m = 0; m < 4; ++m){
      af[m] = *(const short8*)(As + (wr*64 + m*16 + (lane & 15)) * 32 + kro);
      bf[m] = *(const short8*)(Bs + (wc*64 + m*16 + (lane & 15)) * 32 + kro);
    }
    #pragma unroll
    for(int m = 0; m < 4; ++m){
      #pragma unroll
      for(int n = 0; n < 4; ++n){
        acc[m][n] = __builtin_amdgcn_mfma_f32_16x16x32_bf16(af[m], bf[n], acc[m][n], 0, 0, 0);
      }
    }
    __syncthreads();
  }
  const int crow0 = (lane >> 4) * 4;
  const int ccol = lane & 15;
  float fb[4];
  #pragma unroll
  for(int n = 0; n < 4; ++n) fb[n] = fc_b[nbase + wc*64 + n*16 + ccol];
  #pragma unroll
  for(int m = 0; m < 4; ++m){
    #pragma unroll
    for(int j = 0; j < 4; ++j){
      long rr = mbase + wr*64 + m*16 + crow0 + j;
      int t = (int)(rr >> 4), b = (int)(rr & 15);
      float* orow = out + ((long)b * 256 + t) * 32000;
      #pragma unroll
      for(int n = 0; n < 4; ++n){
        float v = (t == 0) ? 0.f : (acc[m][n][j] + fb[n]);
        orow[nbase + wc*64 + n*16 + ccol] = v;
      }
    }
  }
}

extern "C" void kernel_launch(void* const* d_in, const int* in_sizes, int n_in,
                              void* d_out, int out_size, void* d_ws, size_t ws_size,
                              hipStream_t stream){
  const int*   words = (const int*)  d_in[0];
  const float* embed = (const float*)d_in[1];
  const float* fc_b  = (const float*)d_in[2];
  const float* w_ih1 = (const float*)d_in[3];
  const float* w_hh1 = (const float*)d_in[4];
  const float* b_ih1 = (const float*)d_in[5];
  const float* b_hh1 = (const float*)d_in[6];
  const float* w_ih2 = (const float*)d_in[7];
  const float* w_hh2 = (const float*)d_in[8];
  const float* b_ih2 = (const float*)d_in[9];
  const float* b_hh2 = (const float*)d_in[10];
  float* out = (float*)d_out;
  char* ws = (char*)d_ws;

  unsigned short* embed_bf = (unsigned short*)(ws + 0);          // 32,768,000 B
  unsigned short* h2bf     = (unsigned short*)(ws + 32768000);   //  4,194,304 B (4096x512)
  float* h1ring = (float*)(ws + 36962304);                       //  2,097,152 B (64 x 16x512)
  float* h2ring = (float*)(ws + 39059456);                       //     65,536 B (2 x 16x512)
  float* a1c    = (float*)(ws + 39124992);                       //    131,072 B (16x2048)
  float* b2c    = (float*)(ws + 39256064);                       //      8,192 B
  int*   cnts   = (int*)  (ws + 39264256);                       //        256 B
  int* cnt1 = cnts;        // L1 progress
  int* cnt2 = cnts + 32;   // L2 progress (separate cache line)
  // total 39,264,512 B

  k_embed_cvt<<<16000, 256, 0, stream>>>(embed, embed_bf);
  k_prep_misc<<<32, 256, 0, stream>>>(b_ih2, b_hh2, b2c, h1ring, h2ring, h2bf, cnts);
  k_a1const<<<128, 256, 0, stream>>>(words, embed, w_ih1, b_ih1, b_hh1, a1c);

  void* args[10];
  args[0] = (void*)&w_hh1; args[1] = (void*)&w_ih2; args[2] = (void*)&w_hh2;
  args[3] = (void*)&a1c;   args[4] = (void*)&b2c;
  args[5] = (void*)&h1ring; args[6] = (void*)&h2ring; args[7] = (void*)&h2bf;
  args[8] = (void*)&cnt1;  args[9] = (void*)&cnt2;
  hipLaunchCooperativeKernel((const void*)k_recur, dim3(192), dim3(256), args, 0, stream);

  k_proj<<<dim3(250, 32), 256, 0, stream>>>(h2bf, embed_bf, fc_b, out);
}

// Round 4
// 3705.341 us; speedup vs baseline: 3.7048x; 1.1008x over previous
//
#include <hip/hip_runtime.h>

typedef __attribute__((ext_vector_type(8))) short short8;
typedef __attribute__((ext_vector_type(4))) float f32x4;

__device__ __forceinline__ unsigned short f2bf(float f){
  unsigned u = __float_as_uint(f);
  u += 0x7FFFu + ((u >> 16) & 1u);
  return (unsigned short)(u >> 16);
}
__device__ __forceinline__ float sigm(float x){ return 1.f / (1.f + expf(-x)); }
__device__ __forceinline__ int aldr(const int* p){
  return __hip_atomic_load(p, __ATOMIC_RELAXED, __HIP_MEMORY_SCOPE_AGENT);
}

// ---------- prep kernels ----------

__global__ void k_embed_cvt(const float* __restrict__ e, unsigned short* __restrict__ ebf){
  long i = ((long)blockIdx.x * 256 + threadIdx.x) * 4;
  float4 v = *(const float4*)(e + i);
  ushort4 o;
  o.x = f2bf(v.x); o.y = f2bf(v.y); o.z = f2bf(v.z); o.w = f2bf(v.w);
  *(ushort4*)(ebf + i) = o;
}

// zero h1ring slot0, h2ring slot0, h2bf rows t=0, flag slots; b2c = b_ih2+b_hh2
__global__ void k_prep_misc(const float* __restrict__ b_ih2, const float* __restrict__ b_hh2,
                            float* __restrict__ b2c, float* __restrict__ h1ring0,
                            float* __restrict__ h2ring0, unsigned short* __restrict__ h2bf0,
                            int* __restrict__ flags){
  int i = blockIdx.x * 256 + threadIdx.x;
  if(i < 8192){ h1ring0[i] = 0.f; h2ring0[i] = 0.f; h2bf0[i] = 0; }
  if(i < 2048){ b2c[i] = b_ih2[i] + b_hh2[i]; }
  if(i < 192){ flags[i] = 0; }
}

// a1c[b][j] = b_ih1[j] + b_hh1[j] + sum_{k<512} embed[words[b][0]][k] * w_ih1[j][k]
__global__ void k_a1const(const int* __restrict__ words, const float* __restrict__ embed,
                          const float* __restrict__ w_ih1, const float* __restrict__ b_ih1,
                          const float* __restrict__ b_hh1, float* __restrict__ a1c){
  int bb = threadIdx.x & 15, jj = threadIdx.x >> 4;
  int j = blockIdx.x * 16 + jj;
  const float* x0 = embed + (long)words[bb * 256] * 512;
  const float* wr = w_ih1 + (long)j * 1024;
  float acc = 0.f;
  for(int k = 0; k < 512; k += 4){
    float4 a = *(const float4*)(x0 + k);
    float4 b = *(const float4*)(wr + k);
    acc += a.x*b.x + a.y*b.y + a.z*b.z + a.w*b.w;
  }
  a1c[bb * 2048 + j] = acc + b_ih1[j] + b_hh1[j];
}

// ---------- recurrent kernel: weight-stationary, flag slots + R2's fence model ----------
// blocks [0,64): layer-1 (8 units each). blocks [64,192): layer-2 (4 units each).
// Producer: plain stores -> __syncthreads (vmcnt drain) -> RELEASE flag store (wbl2).
// Consumer: wave0 polls flags relaxed -> ACQUIRE fence (buffer_inv) -> barrier -> plain loads.
__global__ void __launch_bounds__(256, 1) k_recur(
    const float* __restrict__ w_hh1, const float* __restrict__ w_ih2, const float* __restrict__ w_hh2,
    const float* __restrict__ a1c, const float* __restrict__ b2c,
    float* __restrict__ h1ring, float* __restrict__ h2ring, unsigned short* __restrict__ h2bf,
    int* done1, int* done2){
  __shared__ float smem[16384];   // 64 KiB
  const int bl = blockIdx.x, tid = threadIdx.x;

  if(bl < 64){
    // ---- layer 1 ----
    const int ubase = bl * 8;
    const int cgrp = tid & 7, kg = (tid >> 3) & 15, bh = tid >> 7;
    const int xr = kg & 7;
    float4 wr[4][8];
    {
      const int j0 = (cgrp >> 1) * 512 + ubase + (cgrp & 1) * 4;
      #pragma unroll
      for(int cc = 0; cc < 4; ++cc)
        #pragma unroll
        for(int j = 0; j < 8; ++j)
          wr[cc][j] = *(const float4*)(w_hh1 + (long)(j0 + cc) * 512 + kg * 32 + j * 4);
    }
    float c1 = 0.f;
    float a1g[4] = {0.f, 0.f, 0.f, 0.f};
    const int au = tid & 7, ab = tid >> 3;
    if(tid < 128){
      #pragma unroll
      for(int g = 0; g < 4; ++g) a1g[g] = a1c[ab * 2048 + g * 512 + ubase + au];
    }
    for(int s = 1; s <= 255; ++s){
      if(tid < 64){
        for(;;){
          int ok = (aldr(done1 + tid) >= s - 1);
          if(s >= 65){
            ok &= (aldr(done2 + tid) >= s - 64);
            ok &= (aldr(done2 + 64 + tid) >= s - 64);
          }
          if(__all(ok)) break;
        }
        __builtin_amdgcn_fence(__ATOMIC_ACQUIRE, "agent");   // buffer_inv: fresh L2
      }
      __syncthreads();
      { // stage h1(s-1): 32 KiB, XOR-swizzled, plain cacheable float4 loads
        const float* src = h1ring + ((s - 1) & 63) * 8192;
        #pragma unroll
        for(int j = 0; j < 8; ++j){
          int v = tid + 256 * j;
          *(float4*)(smem + 4 * (v ^ ((v >> 3) & 7))) = *(const float4*)(src + 4 * v);
        }
      }
      __syncthreads();
      float4 acc[8] = {};
      #pragma unroll
      for(int b8 = 0; b8 < 8; ++b8){
        const int b = bh * 8 + b8;
        const float* hb = smem + b * 512 + kg * 32;
        float4 hv[8];
        #pragma unroll
        for(int j = 0; j < 8; ++j) hv[j] = *(const float4*)(hb + 4 * (j ^ xr));
        #pragma unroll
        for(int j = 0; j < 8; ++j){
          float4 h4 = hv[j];
          acc[b8].x += h4.x*wr[0][j].x + h4.y*wr[0][j].y + h4.z*wr[0][j].z + h4.w*wr[0][j].w;
          acc[b8].y += h4.x*wr[1][j].x + h4.y*wr[1][j].y + h4.z*wr[1][j].z + h4.w*wr[1][j].w;
          acc[b8].z += h4.x*wr[2][j].x + h4.y*wr[2][j].y + h4.z*wr[2][j].z + h4.w*wr[2][j].w;
          acc[b8].w += h4.x*wr[3][j].x + h4.y*wr[3][j].y + h4.z*wr[3][j].z + h4.w*wr[3][j].w;
        }
      }
      __syncthreads();                        // stage reads done -> reuse smem
      #pragma unroll
      for(int b8 = 0; b8 < 8; ++b8){
        int b = bh * 8 + b8;
        *(float4*)(smem + (kg * 16 + b) * 32 + cgrp * 4) = acc[b8];
      }
      __syncthreads();
      #pragma unroll
      for(int q = 0; q < 2; ++q){            // reduce over 16 kg
        int p = tid * 2 + q, b = p >> 5, col = p & 31;
        float sum = 0.f;
        #pragma unroll
        for(int k2 = 0; k2 < 16; ++k2) sum += smem[k2 * 512 + b * 32 + col];
        smem[8192 + b * 32 + col] = sum;
      }
      __syncthreads();
      if(tid < 128){
        float g0 = smem[8192 + ab * 32 +  0 + au] + a1g[0];
        float g1 = smem[8192 + ab * 32 +  8 + au] + a1g[1];
        float g2 = smem[8192 + ab * 32 + 16 + au] + a1g[2];
        float g3 = smem[8192 + ab * 32 + 24 + au] + a1g[3];
        c1 = sigm(g1) * c1 + sigm(g0) * tanhf(g2);
        float h = sigm(g3) * tanhf(c1);
        h1ring[(s & 63) * 8192 + ab * 512 + ubase + au] = h;
      }
      __syncthreads();                        // drains vmcnt(0): stores in L2
      if(tid == 0)
        __hip_atomic_store(done1 + bl, s, __ATOMIC_RELEASE, __HIP_MEMORY_SCOPE_AGENT);
    }
  } else {
    // ---- layer 2 ----
    const int ubase = (bl - 64) * 4;
    const int cgrp = tid & 3, kg = (tid >> 2) & 31, bh = tid >> 7;
    const int xr = kg & 7;
    float4 wr[4][8];   // kg<16 -> w_ih2 (K = h1), else w_hh2 (K = h2prev)
    {
      const float* W = (kg < 16) ? w_ih2 : w_hh2;
      const int ko = (kg & 15) * 32;
      #pragma unroll
      for(int cc = 0; cc < 4; ++cc){
        const int row = cgrp * 512 + ubase + cc;
        #pragma unroll
        for(int j = 0; j < 8; ++j)
          wr[cc][j] = *(const float4*)(W + (long)row * 512 + ko + j * 4);
      }
    }
    float c2 = 0.f;
    float b2g[4] = {0.f, 0.f, 0.f, 0.f};
    const int au = tid & 3, ab = tid >> 2;
    if(tid < 64){
      #pragma unroll
      for(int g = 0; g < 4; ++g) b2g[g] = b2c[g * 512 + ubase + au];
    }
    for(int t = 1; t <= 255; ++t){
      if(tid < 64){
        for(;;){
          int ok = (aldr(done1 + tid) >= t);
          if(t > 1){
            ok &= (aldr(done2 + tid) >= t - 1);
            ok &= (aldr(done2 + 64 + tid) >= t - 1);
          }
          if(__all(ok)) break;
        }
        __builtin_amdgcn_fence(__ATOMIC_ACQUIRE, "agent");
      }
      __syncthreads();
      { // stage [h1(t) | h2(t-1)]: 64 KiB, plain loads; lanes<128 h1 (wave-uniform)
        const float* s1 = h1ring + (t & 63) * 8192;
        const float* s2 = h2ring + ((t - 1) & 1) * 8192;
        #pragma unroll
        for(int j = 0; j < 16; ++j){
          int v = tid + 256 * j;
          float4 val = (tid < 128) ? *(const float4*)(s1 + j * 512 + tid * 4)
                                   : *(const float4*)(s2 + j * 512 + (tid - 128) * 4);
          *(float4*)(smem + 4 * (v ^ ((v >> 3) & 7))) = val;
        }
      }
      __syncthreads();
      float4 acc[8] = {};
      #pragma unroll
      for(int b8 = 0; b8 < 8; ++b8){
        const int b = bh * 8 + b8;
        const float* hb = smem + b * 1024 + kg * 32;
        float4 hv[8];
        #pragma unroll
        for(int j = 0; j < 8; ++j) hv[j] = *(const float4*)(hb + 4 * (j ^ xr));
        #pragma unroll
        for(int j = 0; j < 8; ++j){
          float4 h4 = hv[j];
          acc[b8].x += h4.x*wr[0][j].x + h4.y*wr[0][j].y + h4.z*wr[0][j].z + h4.w*wr[0][j].w;
          acc[b8].y += h4.x*wr[1][j].x + h4.y*wr[1][j].y + h4.z*wr[1][j].z + h4.w*wr[1][j].w;
          acc[b8].z += h4.x*wr[2][j].x + h4.y*wr[2][j].y + h4.z*wr[2][j].z + h4.w*wr[2][j].w;
          acc[b8].w += h4.x*wr[3][j].x + h4.y*wr[3][j].y + h4.z*wr[3][j].z + h4.w*wr[3][j].w;
        }
      }
      __syncthreads();
      #pragma unroll
      for(int b8 = 0; b8 < 8; ++b8){
        int b = bh * 8 + b8;
        *(float4*)(smem + (kg * 16 + b) * 16 + cgrp * 4) = acc[b8];
      }
      __syncthreads();
      {
        int b = tid >> 4, col = tid & 15;
        float sum = 0.f;
        #pragma unroll
        for(int k2 = 0; k2 < 32; ++k2) sum += smem[k2 * 256 + b * 16 + col];
        smem[8192 + b * 16 + col] = sum;
      }
      __syncthreads();
      if(tid < 64){
        float g0 = smem[8192 + ab * 16 +  0 + au] + b2g[0];
        float g1 = smem[8192 + ab * 16 +  4 + au] + b2g[1];
        float g2 = smem[8192 + ab * 16 +  8 + au] + b2g[2];
        float g3 = smem[8192 + ab * 16 + 12 + au] + b2g[3];
        c2 = sigm(g1) * c2 + sigm(g0) * tanhf(g2);
        float h = sigm(g3) * tanhf(c2);
        h2ring[(t & 1) * 8192 + ab * 512 + ubase + au] = h;
        h2bf[((long)t * 16 + ab) * 512 + ubase + au] = f2bf(h);   // read by k_proj only
      }
      __syncthreads();
      if(tid == 0)
        __hip_atomic_store(done2 + (bl - 64), t, __ATOMIC_RELEASE, __HIP_MEMORY_SCOPE_AGENT);
    }
  }
}

// ---------- projection GEMM (unchanged, passing) ----------
__global__ void __launch_bounds__(256, 2) k_proj(const unsigned short* __restrict__ A,
                                                 const unsigned short* __restrict__ Bm,
                                                 const float* __restrict__ fc_b,
                                                 float* __restrict__ out){
  __shared__ __align__(16) unsigned short As[4096];   // [128][32]
  __shared__ __align__(16) unsigned short Bs[4096];   // [128][32]
  const int tid = threadIdx.x;
  const int lane = tid & 63, w = tid >> 6;
  const int wr = w >> 1, wc = w & 1;
  const long mbase = (long)blockIdx.y * 128;
  const long nbase = (long)blockIdx.x * 128;
  f32x4 acc[4][4] = {};

  const int lrow = lane >> 2;
  const int lcol = (lane & 3) * 8;
  for(int kt = 0; kt < 16; ++kt){
    #pragma unroll
    for(int r = 0; r < 2; ++r){
      const unsigned short* ga = A  + (mbase + r*64 + w*16 + lrow) * 512 + kt*32 + lcol;
      __builtin_amdgcn_global_load_lds((const __attribute__((address_space(1))) void*)ga,
          (__attribute__((address_space(3))) void*)((char*)As + r*4096 + w*1024), 16, 0, 0);
      const unsigned short* gb = Bm + (nbase + r*64 + w*16 + lrow) * 512 + kt*32 + lcol;
      __builtin_amdgcn_global_load_lds((const __attribute__((address_space(1))) void*)gb,
          (__attribute__((address_space(3))) void*)((char*)Bs + r*4096 + w*1024), 16, 0, 0);
    }
    __syncthreads();
    short8 af[4], bf[4];
    const int kro = (lane >> 4) * 8;
    #pragma unroll
    for(int m = 0; m < 4; ++m){
      af[m] = *(const short8*)(As + (wr*64 + m*16 + (lane & 15)) * 32 + kro);
      bf[m] = *(const short8*)(Bs + (wc*64 + m*16 + (lane & 15)) * 32 + kro);
    }
    #pragma unroll
    for(int m = 0; m < 4; ++m){
      #pragma unroll
      for(int n = 0; n < 4; ++n){
        acc[m][n] = __builtin_amdgcn_mfma_f32_16x16x32_bf16(af[m], bf[n], acc[m][n], 0, 0, 0);
      }
    }
    __syncthreads();
  }
  const int crow0 = (lane >> 4) * 4;
  const int ccol = lane & 15;
  float fb[4];
  #pragma unroll
  for(int n = 0; n < 4; ++n) fb[n] = fc_b[nbase + wc*64 + n*16 + ccol];
  #pragma unroll
  for(int m = 0; m < 4; ++m){
    #pragma unroll
    for(int j = 0; j < 4; ++j){
      long rr = mbase + wr*64 + m*16 + crow0 + j;
      int t = (int)(rr >> 4), b = (int)(rr & 15);
      float* orow = out + ((long)b * 256 + t) * 32000;
      #pragma unroll
      for(int n = 0; n < 4; ++n){
        float v = (t == 0) ? 0.f : (acc[m][n][j] + fb[n]);
        orow[nbase + wc*64 + n*16 + ccol] = v;
      }
    }
  }
}

extern "C" void kernel_launch(void* const* d_in, const int* in_sizes, int n_in,
                              void* d_out, int out_size, void* d_ws, size_t ws_size,
                              hipStream_t stream){
  const int*   words = (const int*)  d_in[0];
  const float* embed = (const float*)d_in[1];
  const float* fc_b  = (const float*)d_in[2];
  const float* w_ih1 = (const float*)d_in[3];
  const float* w_hh1 = (const float*)d_in[4];
  const float* b_ih1 = (const float*)d_in[5];
  const float* b_hh1 = (const float*)d_in[6];
  const float* w_ih2 = (const float*)d_in[7];
  const float* w_hh2 = (const float*)d_in[8];
  const float* b_ih2 = (const float*)d_in[9];
  const float* b_hh2 = (const float*)d_in[10];
  float* out = (float*)d_out;
  char* ws = (char*)d_ws;

  unsigned short* embed_bf = (unsigned short*)(ws + 0);          // 32,768,000 B
  unsigned short* h2bf     = (unsigned short*)(ws + 32768000);   //  4,194,304 B (4096x512)
  float* h1ring = (float*)(ws + 36962304);                       //  2,097,152 B (64 x 16x512)
  float* h2ring = (float*)(ws + 39059456);                       //     65,536 B (2 x 16x512)
  float* a1c    = (float*)(ws + 39124992);                       //    131,072 B (16x2048)
  float* b2c    = (float*)(ws + 39256064);                       //      8,192 B
  int*   flags  = (int*)  (ws + 39264256);                       //        768 B
  int* done1 = flags;        // [64]
  int* done2 = flags + 64;   // [128]

  k_embed_cvt<<<16000, 256, 0, stream>>>(embed, embed_bf);
  k_prep_misc<<<32, 256, 0, stream>>>(b_ih2, b_hh2, b2c, h1ring, h2ring, h2bf, flags);
  k_a1const<<<128, 256, 0, stream>>>(words, embed, w_ih1, b_ih1, b_hh1, a1c);

  void* args[10];
  args[0] = (void*)&w_hh1; args[1] = (void*)&w_ih2; args[2] = (void*)&w_hh2;
  args[3] = (void*)&a1c;   args[4] = (void*)&b2c;
  args[5] = (void*)&h1ring; args[6] = (void*)&h2ring; args[7] = (void*)&h2bf;
  args[8] = (void*)&done1; args[9] = (void*)&done2;
  hipLaunchCooperativeKernel((const void*)k_recur, dim3(192), dim3(256), args, 0, stream);

  k_proj<<<dim3(250, 32), 256, 0, stream>>>(h2bf, embed_bf, fc_b, out);
}

// Round 7
// 3540.667 us; speedup vs baseline: 3.8771x; 1.0465x over previous
//
#include <hip/hip_runtime.h>

typedef __attribute__((ext_vector_type(8))) short short8;
typedef __attribute__((ext_vector_type(4))) float f32x4;

__device__ __forceinline__ unsigned short f2bf(float f){
  unsigned u = __float_as_uint(f);
  u += 0x7FFFu + ((u >> 16) & 1u);
  return (unsigned short)(u >> 16);
}
__device__ __forceinline__ float sigm(float x){ return 1.f / (1.f + expf(-x)); }
__device__ __forceinline__ int aldr(const int* p){
  return __hip_atomic_load(p, __ATOMIC_RELAXED, __HIP_MEMORY_SCOPE_AGENT);
}

// ---------- prep kernels ----------

__global__ void k_embed_cvt(const float* __restrict__ e, unsigned short* __restrict__ ebf){
  long i = ((long)blockIdx.x * 256 + threadIdx.x) * 4;
  float4 v = *(const float4*)(e + i);
  ushort4 o;
  o.x = f2bf(v.x); o.y = f2bf(v.y); o.z = f2bf(v.z); o.w = f2bf(v.w);
  *(ushort4*)(ebf + i) = o;
}

// zero h1ring slot0, h2ring slot0, h2bf rows t=0, flag slots; b2c = b_ih2+b_hh2
__global__ void k_prep_misc(const float* __restrict__ b_ih2, const float* __restrict__ b_hh2,
                            float* __restrict__ b2c, float* __restrict__ h1ring0,
                            float* __restrict__ h2ring0, unsigned short* __restrict__ h2bf0,
                            int* __restrict__ flags){
  int i = blockIdx.x * 256 + threadIdx.x;
  if(i < 8192){ h1ring0[i] = 0.f; h2ring0[i] = 0.f; h2bf0[i] = 0; }
  if(i < 2048){ b2c[i] = b_ih2[i] + b_hh2[i]; }
  if(i < 192){ flags[i] = 0; }
}

// a1c[b][j] = b_ih1[j] + b_hh1[j] + sum_{k<512} embed[words[b][0]][k] * w_ih1[j][k]
__global__ void k_a1const(const int* __restrict__ words, const float* __restrict__ embed,
                          const float* __restrict__ w_ih1, const float* __restrict__ b_ih1,
                          const float* __restrict__ b_hh1, float* __restrict__ a1c){
  int bb = threadIdx.x & 15, jj = threadIdx.x >> 4;
  int j = blockIdx.x * 16 + jj;
  const float* x0 = embed + (long)words[bb * 256] * 512;
  const float* wr = w_ih1 + (long)j * 1024;
  float acc = 0.f;
  for(int k = 0; k < 512; k += 4){
    float4 a = *(const float4*)(x0 + k);
    float4 b = *(const float4*)(wr + k);
    acc += a.x*b.x + a.y*b.y + a.z*b.z + a.w*b.w;
  }
  a1c[bb * 2048 + j] = acc + b_ih1[j] + b_hh1[j];
}

// ---------- recurrent kernel: weight-stationary (for real this time), R4's proven sync ----------
// waves_per_eu(1,1): RA may use up to 512 VGPRs so wr[4][8] (128 VGPR) stays register-resident
// across all 255 steps. Occupancy 1 block/CU is fine: cooperative 192 blocks <= 256 CUs.
__global__ void __attribute__((amdgpu_flat_work_group_size(256,256), amdgpu_waves_per_eu(1,1)))
k_recur(
    const float* __restrict__ w_hh1, const float* __restrict__ w_ih2, const float* __restrict__ w_hh2,
    const float* __restrict__ a1c, const float* __restrict__ b2c,
    float* __restrict__ h1ring, float* __restrict__ h2ring, unsigned short* __restrict__ h2bf,
    int* done1, int* done2){
  __shared__ float smem[16384];   // 64 KiB
  const int bl = blockIdx.x, tid = threadIdx.x;

  if(bl < 64){
    // ---- layer 1 ----
    const int ubase = bl * 8;
    const int cgrp = tid & 7, kg = (tid >> 3) & 15, bh = tid >> 7;
    const int xr = kg & 7;
    float4 wr[4][8];
    {
      const int j0 = (cgrp >> 1) * 512 + ubase + (cgrp & 1) * 4;
      #pragma unroll
      for(int cc = 0; cc < 4; ++cc)
        #pragma unroll
        for(int j = 0; j < 8; ++j)
          wr[cc][j] = *(const float4*)(w_hh1 + (long)(j0 + cc) * 512 + kg * 32 + j * 4);
    }
    float c1 = 0.f;
    float a1g[4] = {0.f, 0.f, 0.f, 0.f};
    const int au = tid & 7, ab = tid >> 3;
    if(tid < 128){
      #pragma unroll
      for(int g = 0; g < 4; ++g) a1g[g] = a1c[ab * 2048 + g * 512 + ubase + au];
    }
    for(int s = 1; s <= 255; ++s){
      if(tid < 64){
        for(;;){
          int ok = (aldr(done1 + tid) >= s - 1);
          if(s >= 65){
            ok &= (aldr(done2 + tid) >= s - 64);
            ok &= (aldr(done2 + 64 + tid) >= s - 64);
          }
          if(__all(ok)) break;
        }
        __builtin_amdgcn_fence(__ATOMIC_ACQUIRE, "agent");   // buffer_inv: fresh L2
      }
      __syncthreads();
      { // stage h1(s-1): 32 KiB, XOR-swizzled, plain cacheable float4 loads
        const float* src = h1ring + ((s - 1) & 63) * 8192;
        #pragma unroll
        for(int j = 0; j < 8; ++j){
          int v = tid + 256 * j;
          *(float4*)(smem + 4 * (v ^ ((v >> 3) & 7))) = *(const float4*)(src + 4 * v);
        }
      }
      __syncthreads();
      float4 acc[8] = {};
      #pragma unroll
      for(int b8 = 0; b8 < 8; ++b8){
        const int b = bh * 8 + b8;
        const float* hb = smem + b * 512 + kg * 32;
        float4 hv[8];
        #pragma unroll
        for(int j = 0; j < 8; ++j) hv[j] = *(const float4*)(hb + 4 * (j ^ xr));
        #pragma unroll
        for(int j = 0; j < 8; ++j){
          float4 h4 = hv[j];
          acc[b8].x += h4.x*wr[0][j].x + h4.y*wr[0][j].y + h4.z*wr[0][j].z + h4.w*wr[0][j].w;
          acc[b8].y += h4.x*wr[1][j].x + h4.y*wr[1][j].y + h4.z*wr[1][j].z + h4.w*wr[1][j].w;
          acc[b8].z += h4.x*wr[2][j].x + h4.y*wr[2][j].y + h4.z*wr[2][j].z + h4.w*wr[2][j].w;
          acc[b8].w += h4.x*wr[3][j].x + h4.y*wr[3][j].y + h4.z*wr[3][j].z + h4.w*wr[3][j].w;
        }
      }
      __syncthreads();                        // stage reads done -> reuse smem
      #pragma unroll
      for(int b8 = 0; b8 < 8; ++b8){
        int b = bh * 8 + b8;
        *(float4*)(smem + (kg * 16 + b) * 32 + cgrp * 4) = acc[b8];
      }
      __syncthreads();
      #pragma unroll
      for(int q = 0; q < 2; ++q){            // reduce over 16 kg
        int p = tid * 2 + q, b = p >> 5, col = p & 31;
        float sum = 0.f;
        #pragma unroll
        for(int k2 = 0; k2 < 16; ++k2) sum += smem[k2 * 512 + b * 32 + col];
        smem[8192 + b * 32 + col] = sum;
      }
      __syncthreads();
      if(tid < 128){
        float g0 = smem[8192 + ab * 32 +  0 + au] + a1g[0];
        float g1 = smem[8192 + ab * 32 +  8 + au] + a1g[1];
        float g2 = smem[8192 + ab * 32 + 16 + au] + a1g[2];
        float g3 = smem[8192 + ab * 32 + 24 + au] + a1g[3];
        c1 = sigm(g1) * c1 + sigm(g0) * tanhf(g2);
        float h = sigm(g3) * tanhf(c1);
        h1ring[(s & 63) * 8192 + ab * 512 + ubase + au] = h;
      }
      __syncthreads();                        // drains vmcnt(0): stores in L2
      if(tid == 0)
        __hip_atomic_store(done1 + bl, s, __ATOMIC_RELEASE, __HIP_MEMORY_SCOPE_AGENT);
    }
  } else {
    // ---- layer 2 ----
    const int ubase = (bl - 64) * 4;
    const int cgrp = tid & 3, kg = (tid >> 2) & 31, bh = tid >> 7;
    const int xr = kg & 7;
    float4 wr[4][8];   // kg<16 -> w_ih2 (K = h1), else w_hh2 (K = h2prev)
    {
      const float* W = (kg < 16) ? w_ih2 : w_hh2;
      const int ko = (kg & 15) * 32;
      #pragma unroll
      for(int cc = 0; cc < 4; ++cc){
        const int row = cgrp * 512 + ubase + cc;
        #pragma unroll
        for(int j = 0; j < 8; ++j)
          wr[cc][j] = *(const float4*)(W + (long)row * 512 + ko + j * 4);
      }
    }
    float c2 = 0.f;
    float b2g[4] = {0.f, 0.f, 0.f, 0.f};
    const int au = tid & 3, ab = tid >> 2;
    if(tid < 64){
      #pragma unroll
      for(int g = 0; g < 4; ++g) b2g[g] = b2c[g * 512 + ubase + au];
    }
    for(int t = 1; t <= 255; ++t){
      if(tid < 64){
        for(;;){
          int ok = (aldr(done1 + tid) >= t);
          if(t > 1){
            ok &= (aldr(done2 + tid) >= t - 1);
            ok &= (aldr(done2 + 64 + tid) >= t - 1);
          }
          if(__all(ok)) break;
        }
        __builtin_amdgcn_fence(__ATOMIC_ACQUIRE, "agent");
      }
      __syncthreads();
      { // stage [h1(t) | h2(t-1)]: 64 KiB, plain loads; lanes<128 h1 (wave-uniform)
        const float* s1 = h1ring + (t & 63) * 8192;
        const float* s2 = h2ring + ((t - 1) & 1) * 8192;
        #pragma unroll
        for(int j = 0; j < 16; ++j){
          int v = tid + 256 * j;
          float4 val = (tid < 128) ? *(const float4*)(s1 + j * 512 + tid * 4)
                                   : *(const float4*)(s2 + j * 512 + (tid - 128) * 4);
          *(float4*)(smem + 4 * (v ^ ((v >> 3) & 7))) = val;
        }
      }
      __syncthreads();
      float4 acc[8] = {};
      #pragma unroll
      for(int b8 = 0; b8 < 8; ++b8){
        const int b = bh * 8 + b8;
        const float* hb = smem + b * 1024 + kg * 32;
        float4 hv[8];
        #pragma unroll
        for(int j = 0; j < 8; ++j) hv[j] = *(const float4*)(hb + 4 * (j ^ xr));
        #pragma unroll
        for(int j = 0; j < 8; ++j){
          float4 h4 = hv[j];
          acc[b8].x += h4.x*wr[0][j].x + h4.y*wr[0][j].y + h4.z*wr[0][j].z + h4.w*wr[0][j].w;
          acc[b8].y += h4.x*wr[1][j].x + h4.y*wr[1][j].y + h4.z*wr[1][j].z + h4.w*wr[1][j].w;
          acc[b8].z += h4.x*wr[2][j].x + h4.y*wr[2][j].y + h4.z*wr[2][j].z + h4.w*wr[2][j].w;
          acc[b8].w += h4.x*wr[3][j].x + h4.y*wr[3][j].y + h4.z*wr[3][j].z + h4.w*wr[3][j].w;
        }
      }
      __syncthreads();
      #pragma unroll
      for(int b8 = 0; b8 < 8; ++b8){
        int b = bh * 8 + b8;
        *(float4*)(smem + (kg * 16 + b) * 16 + cgrp * 4) = acc[b8];
      }
      __syncthreads();
      {
        int b = tid >> 4, col = tid & 15;
        float sum = 0.f;
        #pragma unroll
        for(int k2 = 0; k2 < 32; ++k2) sum += smem[k2 * 256 + b * 16 + col];
        smem[8192 + b * 16 + col] = sum;
      }
      __syncthreads();
      if(tid < 64){
        float g0 = smem[8192 + ab * 16 +  0 + au] + b2g[0];
        float g1 = smem[8192 + ab * 16 +  4 + au] + b2g[1];
        float g2 = smem[8192 + ab * 16 +  8 + au] + b2g[2];
        float g3 = smem[8192 + ab * 16 + 12 + au] + b2g[3];
        c2 = sigm(g1) * c2 + sigm(g0) * tanhf(g2);
        float h = sigm(g3) * tanhf(c2);
        h2ring[(t & 1) * 8192 + ab * 512 + ubase + au] = h;
        h2bf[((long)t * 16 + ab) * 512 + ubase + au] = f2bf(h);   // read by k_proj only
      }
      __syncthreads();
      if(tid == 0)
        __hip_atomic_store(done2 + (bl - 64), t, __ATOMIC_RELEASE, __HIP_MEMORY_SCOPE_AGENT);
    }
  }
}

// ---------- projection GEMM (unchanged, passing) ----------
__global__ void __launch_bounds__(256, 2) k_proj(const unsigned short* __restrict__ A,
                                                 const unsigned short* __restrict__ Bm,
                                                 const float* __restrict__ fc_b,
                                                 float* __restrict__ out){
  __shared__ __align__(16) unsigned short As[4096];   // [128][32]
  __shared__ __align__(16) unsigned short Bs[4096];   // [128][32]
  const int tid = threadIdx.x;
  const int lane = tid & 63, w = tid >> 6;
  const int wr = w >> 1, wc = w & 1;
  const long mbase = (long)blockIdx.y * 128;
  const long nbase = (long)blockIdx.x * 128;
  f32x4 acc[4][4] = {};

  const int lrow = lane >> 2;
  const int lcol = (lane & 3) * 8;
  for(int kt = 0; kt < 16; ++kt){
    #pragma unroll
    for(int r = 0; r < 2; ++r){
      const unsigned short* ga = A  + (mbase + r*64 + w*16 + lrow) * 512 + kt*32 + lcol;
      __builtin_amdgcn_global_load_lds((const __attribute__((address_space(1))) void*)ga,
          (__attribute__((address_space(3))) void*)((char*)As + r*4096 + w*1024), 16, 0, 0);
      const unsigned short* gb = Bm + (nbase + r*64 + w*16 + lrow) * 512 + kt*32 + lcol;
      __builtin_amdgcn_global_load_lds((const __attribute__((address_space(1))) void*)gb,
          (__attribute__((address_space(3))) void*)((char*)Bs + r*4096 + w*1024), 16, 0, 0);
    }
    __syncthreads();
    short8 af[4], bf[4];
    const int kro = (lane >> 4) * 8;
    #pragma unroll
    for(int m = 0; m < 4; ++m){
      af[m] = *(const short8*)(As + (wr*64 + m*16 + (lane & 15)) * 32 + kro);
      bf[m] = *(const short8*)(Bs + (wc*64 + m*16 + (lane & 15)) * 32 + kro);
    }
    #pragma unroll
    for(int m = 0; m < 4; ++m){
      #pragma unroll
      for(int n = 0; n < 4; ++n){
        acc[m][n] = __builtin_amdgcn_mfma_f32_16x16x32_bf16(af[m], bf[n], acc[m][n], 0, 0, 0);
      }
    }
    __syncthreads();
  }
  const int crow0 = (lane >> 4) * 4;
  const int ccol = lane & 15;
  float fb[4];
  #pragma unroll
  for(int n = 0; n < 4; ++n) fb[n] = fc_b[nbase + wc*64 + n*16 + ccol];
  #pragma unroll
  for(int m = 0; m < 4; ++m){
    #pragma unroll
    for(int j = 0; j < 4; ++j){
      long rr = mbase + wr*64 + m*16 + crow0 + j;
      int t = (int)(rr >> 4), b = (int)(rr & 15);
      float* orow = out + ((long)b * 256 + t) * 32000;
      #pragma unroll
      for(int n = 0; n < 4; ++n){
        float v = (t == 0) ? 0.f : (acc[m][n][j] + fb[n]);
        orow[nbase + wc*64 + n*16 + ccol] = v;
      }
    }
  }
}

extern "C" void kernel_launch(void* const* d_in, const int* in_sizes, int n_in,
                              void* d_out, int out_size, void* d_ws, size_t ws_size,
                              hipStream_t stream){
  const int*   words = (const int*)  d_in[0];
  const float* embed = (const float*)d_in[1];
  const float* fc_b  = (const float*)d_in[2];
  const float* w_ih1 = (const float*)d_in[3];
  const float* w_hh1 = (const float*)d_in[4];
  const float* b_ih1 = (const float*)d_in[5];
  const float* b_hh1 = (const float*)d_in[6];
  const float* w_ih2 = (const float*)d_in[7];
  const float* w_hh2 = (const float*)d_in[8];
  const float* b_ih2 = (const float*)d_in[9];
  const float* b_hh2 = (const float*)d_in[10];
  float* out = (float*)d_out;
  char* ws = (char*)d_ws;

  unsigned short* embed_bf = (unsigned short*)(ws + 0);          // 32,768,000 B
  unsigned short* h2bf     = (unsigned short*)(ws + 32768000);   //  4,194,304 B (4096x512)
  float* h1ring = (float*)(ws + 36962304);                       //  2,097,152 B (64 x 16x512)
  float* h2ring = (float*)(ws + 39059456);                       //     65,536 B (2 x 16x512)
  float* a1c    = (float*)(ws + 39124992);                       //    131,072 B (16x2048)
  float* b2c    = (float*)(ws + 39256064);                       //      8,192 B
  int*   flags  = (int*)  (ws + 39264256);                       //        768 B
  int* done1 = flags;        // [64]
  int* done2 = flags + 64;   // [128]

  k_embed_cvt<<<16000, 256, 0, stream>>>(embed, embed_bf);
  k_prep_misc<<<32, 256, 0, stream>>>(b_ih2, b_hh2, b2c, h1ring, h2ring, h2bf, flags);
  k_a1const<<<128, 256, 0, stream>>>(words, embed, w_ih1, b_ih1, b_hh1, a1c);

  void* args[10];
  args[0] = (void*)&w_hh1; args[1] = (void*)&w_ih2; args[2] = (void*)&w_hh2;
  args[3] = (void*)&a1c;   args[4] = (void*)&b2c;
  args[5] = (void*)&h1ring; args[6] = (void*)&h2ring; args[7] = (void*)&h2bf;
  args[8] = (void*)&done1; args[9] = (void*)&done2;
  hipLaunchCooperativeKernel((const void*)k_recur, dim3(192), dim3(256), args, 0, stream);

  k_proj<<<dim3(250, 32), 256, 0, stream>>>(h2bf, embed_bf, fc_b, out);
}